// Round 3
// baseline (1869.481 us; speedup 1.0000x reference)
//
#include <hip/hip_runtime.h>
#include <hip/hip_bf16.h>
#include <cstddef>
#include <cstdint>

#define IN_C 256
#define OUT_C 64
#define NEG_SLOPE 0.2f
#define TILE 16        // nodes per block-tile in projection kernel
#define BKT 128        // nodes per destination bucket (bucket = c >> 7)
#define PCHUNK 16384   // edges per block in hist/partition kernels
#define MAXB 1024      // LDS array size (>= number of buckets)

__device__ __forceinline__ float lrelu_exp(float t)
{
    t = (t >= 0.f) ? t : NEG_SLOPE * t;
    return __expf(t);
}

__device__ __forceinline__ float bf2f(ushort u)
{
    return __uint_as_float(((uint32_t)u) << 16);
}

__device__ __forceinline__ ushort f2bf(float f)
{
    uint32_t u = __float_as_uint(f);
    u += 0x7fffu + ((u >> 16) & 1u);   // round-to-nearest-even
    return (ushort)(u >> 16);
}

// ---------------------------------------------------------------------------
// Kernel 1: h = x @ W^T (bf16 out), s_i = h@a_i, s_j = h@a_j (fp32).
// W^T (64 KB) + x tile (16 KB) in LDS = 80 KB -> 2 blocks/CU.
// ---------------------------------------------------------------------------
__global__ __launch_bounds__(256) void fused_h_kernel(
    const float* __restrict__ x, const float* __restrict__ W,
    const float* __restrict__ a, ushort* __restrict__ hb,
    float* __restrict__ s_i, float* __restrict__ s_j, int n_nodes)
{
    __shared__ float Wt[IN_C * OUT_C];   // Wt[k*64 + c] = W[c][k]
    __shared__ float xs[TILE * IN_C];

    const int tid = threadIdx.x;
    for (int i = tid; i < OUT_C * IN_C; i += 256) {
        int c = i >> 8;
        int k = i & (IN_C - 1);
        Wt[k * OUT_C + c] = W[i];
    }
    // Wt-use protected by the __syncthreads() after xs staging below.

    const int lane = tid & 63;
    const int wv   = tid >> 6;
    const float ai = a[lane];
    const float aj = a[OUT_C + lane];

    const int tiles = (n_nodes + TILE - 1) / TILE;
    for (int t = blockIdx.x; t < tiles; t += gridDim.x) {
        const int base = t * TILE;
        __syncthreads();
        for (int i = tid; i < TILE * (IN_C / 4); i += 256) {
            const int node = base + (i >> 6);
            const int k4   = i & 63;
            float4 v = make_float4(0.f, 0.f, 0.f, 0.f);
            if (node < n_nodes)
                v = ((const float4*)x)[(size_t)node * (IN_C / 4) + k4];
            ((float4*)xs)[i] = v;
        }
        __syncthreads();

        float acc[4] = {0.f, 0.f, 0.f, 0.f};
        for (int k = 0; k < IN_C; k += 4) {
            const float w0 = Wt[(k + 0) * OUT_C + lane];
            const float w1 = Wt[(k + 1) * OUT_C + lane];
            const float w2 = Wt[(k + 2) * OUT_C + lane];
            const float w3 = Wt[(k + 3) * OUT_C + lane];
            #pragma unroll
            for (int m = 0; m < 4; ++m) {
                const float4 xv = ((const float4*)xs)[(wv * 4 + m) * (IN_C / 4) + (k >> 2)];
                acc[m] += xv.x * w0 + xv.y * w1 + xv.z * w2 + xv.w * w3;
            }
        }

        #pragma unroll
        for (int m = 0; m < 4; ++m) {
            const int node = base + wv * 4 + m;
            const float hv = acc[m];
            float pi = hv * ai;
            float pj = hv * aj;
            #pragma unroll
            for (int off = 32; off > 0; off >>= 1) {
                pi += __shfl_xor(pi, off, 64);
                pj += __shfl_xor(pj, off, 64);
            }
            if (node < n_nodes) {
                hb[(size_t)node * OUT_C + lane] = f2bf(hv);
                if (lane == 0) { s_i[node] = pi; s_j[node] = pj; }
            }
        }
    }
}

// ---------------------------------------------------------------------------
// Bucket histogram: LDS-privatized counts over NB buckets, flush via atomics.
// ---------------------------------------------------------------------------
__global__ __launch_bounds__(256) void zero_kernel(int* __restrict__ p, int n)
{
    const int i = blockIdx.x * 256 + threadIdx.x;
    if (i < n) p[i] = 0;
}

__global__ __launch_bounds__(256) void hist_bucket_kernel(
    const int* __restrict__ ei, int* __restrict__ counts, int n_edges, int nb)
{
    __shared__ int hist[MAXB];
    const int tid  = threadIdx.x;
    const int base = blockIdx.x * PCHUNK;
    const int lim  = min(PCHUNK, n_edges - base);

    for (int i = tid; i < nb; i += 256) hist[i] = 0;
    __syncthreads();
    for (int i = tid; i < lim; i += 256)
        atomicAdd(&hist[ei[n_edges + base + i] >> 7], 1);
    __syncthreads();
    for (int i = tid; i < nb; i += 256) {
        const int c = hist[i];
        if (c > 0) atomicAdd(&counts[i], c);
    }
}

// ---------------------------------------------------------------------------
// Exclusive scan over bucket counts (single block, nb <= 1024).
// Writes offsets and initializes cursor.
// ---------------------------------------------------------------------------
__global__ __launch_bounds__(256) void scan_buckets_kernel(
    const int* __restrict__ counts, int* __restrict__ offsets,
    int* __restrict__ cursor, int nb)
{
    __shared__ int sd[256];
    const int tid  = threadIdx.x;
    const int base = tid * 4;
    int v[4]; int ts = 0;
    #pragma unroll
    for (int j = 0; j < 4; ++j) {
        const int i = base + j;
        v[j] = (i < nb) ? counts[i] : 0;
        ts += v[j];
    }
    sd[tid] = ts;
    __syncthreads();
    for (int off = 1; off < 256; off <<= 1) {
        const int mine  = sd[tid];
        const int other = (tid >= off) ? sd[tid - off] : 0;
        __syncthreads();
        sd[tid] = mine + other;
        __syncthreads();
    }
    int run = sd[tid] - ts;
    #pragma unroll
    for (int j = 0; j < 4; ++j) {
        const int i = base + j;
        if (i < nb) { offsets[i] = run; cursor[i] = run; }
        run += v[j];
    }
}

// ---------------------------------------------------------------------------
// Partition: per-block two-phase (LDS hist -> bulk reserve -> write).
// Record = {r<<7 | (c&127), exp(lrelu(s_i[c]+s_j[r]))}, 8 B.  Each block's
// run within a bucket is exclusive and contiguous -> full-line writes.
// ---------------------------------------------------------------------------
__global__ __launch_bounds__(256) void partition_kernel(
    const int* __restrict__ ei, const float* __restrict__ s_i,
    const float* __restrict__ s_j, int* __restrict__ cursor,
    uint2* __restrict__ rec, int n_edges, int nb)
{
    __shared__ int hist[MAXB];
    __shared__ int lcur[MAXB];
    const int tid  = threadIdx.x;
    const int base = blockIdx.x * PCHUNK;
    const int lim  = min(PCHUNK, n_edges - base);

    for (int i = tid; i < nb; i += 256) hist[i] = 0;
    __syncthreads();
    for (int i = tid; i < lim; i += 256)
        atomicAdd(&hist[ei[n_edges + base + i] >> 7], 1);
    __syncthreads();
    for (int i = tid; i < nb; i += 256) {
        const int c = hist[i];
        lcur[i] = (c > 0) ? atomicAdd(&cursor[i], c) : 0;
    }
    __syncthreads();
    for (int i = tid; i < lim; i += 256) {
        const int r  = ei[base + i];
        const int c  = ei[n_edges + base + i];
        const float ex = lrelu_exp(s_i[c] + s_j[r]);
        const int pos = atomicAdd(&lcur[c >> 7], 1);
        rec[pos] = make_uint2(((uint32_t)r << 7) | (uint32_t)(c & (BKT - 1)),
                              __float_as_uint(ex));
    }
}

// ---------------------------------------------------------------------------
// Bucket gather: one block per 128-node bucket.  LDS fp32 accumulators,
// edge-parallel with wave broadcast, bf16 h gathers (2 lines/edge),
// self-loop + normalize in epilogue.  No global atomics.
// ---------------------------------------------------------------------------
__global__ __launch_bounds__(256) void bucket_gather_kernel(
    const uint2* __restrict__ rec, const ushort* __restrict__ hb,
    const float* __restrict__ s_i, const float* __restrict__ s_j,
    const int* __restrict__ offsets, const int* __restrict__ counts,
    float* __restrict__ out, int n_nodes)
{
    __shared__ float acc[BKT * OUT_C];   // 32 KB
    __shared__ float den[BKT];

    const int b    = blockIdx.x;
    const int tid  = threadIdx.x;
    const int lane = tid & 63;
    const int wv   = tid >> 6;

    for (int i = tid; i < BKT * OUT_C; i += 256) acc[i] = 0.f;
    for (int i = tid; i < BKT; i += 256) den[i] = 0.f;
    __syncthreads();

    const int start = offsets[b];
    const int cnt   = counts[b];
    const int nbatch = (cnt + 63) >> 6;

    for (int batch = wv; batch < nbatch; batch += 4) {
        const int e0 = batch << 6;
        const int m  = min(64, cnt - e0);
        uint32_t pk = 0; float ex = 0.f;
        if (lane < m) {
            const uint2 rv = rec[start + e0 + lane];
            pk = rv.x;
            ex = __uint_as_float(rv.y);
        }
        int j = 0;
        for (; j + 8 <= m; j += 8) {
            uint32_t p[8]; float xw[8];
            #pragma unroll
            for (int q = 0; q < 8; ++q) {
                p[q]  = __shfl(pk, j + q, 64);
                xw[q] = __shfl(ex, j + q, 64);
            }
            float hv[8];
            #pragma unroll
            for (int q = 0; q < 8; ++q)
                hv[q] = bf2f(hb[(size_t)(p[q] >> 7) * OUT_C + lane]);
            #pragma unroll
            for (int q = 0; q < 8; ++q) {
                atomicAdd(&acc[(p[q] & (BKT - 1)) * OUT_C + lane], xw[q] * hv[q]);
                if (lane == 0) atomicAdd(&den[p[q] & (BKT - 1)], xw[q]);
            }
        }
        for (; j < m; ++j) {
            const uint32_t p = __shfl(pk, j, 64);
            const float xw   = __shfl(ex, j, 64);
            const float hv   = bf2f(hb[(size_t)(p >> 7) * OUT_C + lane]);
            atomicAdd(&acc[(p & (BKT - 1)) * OUT_C + lane], xw * hv);
            if (lane == 0) atomicAdd(&den[p & (BKT - 1)], xw);
        }
    }
    __syncthreads();

    // epilogue: self-loop + normalize + write
    for (int n = wv; n < BKT; n += 4) {
        const int g = b * BKT + n;
        if (g < n_nodes) {
            const float ex0 = lrelu_exp(s_i[g] + s_j[g]);
            const float hv  = bf2f(hb[(size_t)g * OUT_C + lane]);
            const float d   = den[n] + ex0;
            out[(size_t)g * OUT_C + lane] = (acc[n * OUT_C + lane] + ex0 * hv) / d;
        }
    }
}

extern "C" void kernel_launch(void* const* d_in, const int* in_sizes, int n_in,
                              void* d_out, int out_size, void* d_ws, size_t ws_size,
                              hipStream_t stream)
{
    const float* x  = (const float*)d_in[0];
    const int*   ei = (const int*)d_in[1];
    const float* W  = (const float*)d_in[2];
    const float* a  = (const float*)d_in[3];

    const int N = in_sizes[0] / IN_C;   // 100000
    const int E = in_sizes[1] / 2;      // 3200000
    const int NB = (N + BKT - 1) / BKT; // 782

    float* out = (float*)d_out;

    // workspace carve-up
    char* ws = (char*)d_ws;
    ushort* hb     = (ushort*)ws;                    ws += (size_t)N * OUT_C * 2;  // 12.8 MB
    float*  s_i    = (float*)ws;                     ws += (size_t)N * 4;
    float*  s_j    = (float*)ws;                     ws += (size_t)N * 4;
    int*    counts = (int*)ws;                       ws += (size_t)NB * 4;
    int*    offs   = (int*)ws;                       ws += (size_t)NB * 4;
    int*    cursor = (int*)ws;                       ws += (size_t)NB * 4;
    ws = (char*)(((uintptr_t)ws + 15) & ~(uintptr_t)15);
    uint2*  rec    = (uint2*)ws;                     // E * 8 B = 25.6 MB

    // 1. projection + attention scores
    hipLaunchKernelGGL(fused_h_kernel, dim3(512), dim3(256), 0, stream,
                       x, W, a, hb, s_i, s_j, N);

    // 2. bucket partition of edges
    hipLaunchKernelGGL(zero_kernel, dim3((NB + 255) / 256), dim3(256), 0, stream,
                       counts, NB);
    const int pblocks = (E + PCHUNK - 1) / PCHUNK;
    hipLaunchKernelGGL(hist_bucket_kernel, dim3(pblocks), dim3(256), 0, stream,
                       ei, counts, E, NB);
    hipLaunchKernelGGL(scan_buckets_kernel, dim3(1), dim3(256), 0, stream,
                       counts, offs, cursor, NB);
    hipLaunchKernelGGL(partition_kernel, dim3(pblocks), dim3(256), 0, stream,
                       ei, s_i, s_j, cursor, rec, E, NB);

    // 3. bucket gather-aggregate (LDS accumulators, no global atomics)
    hipLaunchKernelGGL(bucket_gather_kernel, dim3(NB), dim3(256), 0, stream,
                       rec, hb, s_i, s_j, offs, counts, out, N);
}

// Round 4
// 529.906 us; speedup vs baseline: 3.5279x; 3.5279x over previous
//
#include <hip/hip_runtime.h>
#include <hip/hip_bf16.h>
#include <cstddef>
#include <cstdint>

#define IN_C 256
#define OUT_C 64
#define NEG_SLOPE 0.2f
#define TILE 16        // nodes per block-tile in projection kernel
#define BKT 128        // nodes per destination bucket (bucket = c >> 7)
#define PCHUNK 8192    // edges per block in hist/partition kernels
#define MAXB 1024      // LDS array size (>= number of buckets)
#define CAP 8192       // max records/bucket in refine (mean 4092, +64 sigma)

__device__ __forceinline__ float lrelu_exp(float t)
{
    t = (t >= 0.f) ? t : NEG_SLOPE * t;
    return __expf(t);
}

__device__ __forceinline__ float bf2f(ushort u)
{
    return __uint_as_float(((uint32_t)u) << 16);
}

__device__ __forceinline__ ushort f2bf(float f)
{
    uint32_t u = __float_as_uint(f);
    u += 0x7fffu + ((u >> 16) & 1u);   // round-to-nearest-even
    return (ushort)(u >> 16);
}

// ---------------------------------------------------------------------------
// Kernel 1: h = x @ W^T (bf16 out), s_i = h@a_i, s_j = h@a_j (fp32).
// W^T (64 KB) + x tile (16 KB) in LDS; 2 blocks/CU.
// ---------------------------------------------------------------------------
__global__ __launch_bounds__(256) void fused_h_kernel(
    const float* __restrict__ x, const float* __restrict__ W,
    const float* __restrict__ a, ushort* __restrict__ hb,
    float* __restrict__ s_i, float* __restrict__ s_j, int n_nodes)
{
    __shared__ float Wt[IN_C * OUT_C];   // Wt[k*64 + c] = W[c][k]
    __shared__ float xs[TILE * IN_C];

    const int tid = threadIdx.x;
    for (int i = tid; i < OUT_C * IN_C; i += 256) {
        int c = i >> 8;
        int k = i & (IN_C - 1);
        Wt[k * OUT_C + c] = W[i];
    }
    // Wt-use protected by the __syncthreads() after xs staging below.

    const int lane = tid & 63;
    const int wv   = tid >> 6;
    const float ai = a[lane];
    const float aj = a[OUT_C + lane];

    const int tiles = (n_nodes + TILE - 1) / TILE;
    for (int t = blockIdx.x; t < tiles; t += gridDim.x) {
        const int base = t * TILE;
        __syncthreads();
        for (int i = tid; i < TILE * (IN_C / 4); i += 256) {
            const int node = base + (i >> 6);
            const int k4   = i & 63;
            float4 v = make_float4(0.f, 0.f, 0.f, 0.f);
            if (node < n_nodes)
                v = ((const float4*)x)[(size_t)node * (IN_C / 4) + k4];
            ((float4*)xs)[i] = v;
        }
        __syncthreads();

        float acc[4] = {0.f, 0.f, 0.f, 0.f};
        for (int k = 0; k < IN_C; k += 4) {
            const float w0 = Wt[(k + 0) * OUT_C + lane];
            const float w1 = Wt[(k + 1) * OUT_C + lane];
            const float w2 = Wt[(k + 2) * OUT_C + lane];
            const float w3 = Wt[(k + 3) * OUT_C + lane];
            #pragma unroll
            for (int m = 0; m < 4; ++m) {
                const float4 xv = ((const float4*)xs)[(wv * 4 + m) * (IN_C / 4) + (k >> 2)];
                acc[m] += xv.x * w0 + xv.y * w1 + xv.z * w2 + xv.w * w3;
            }
        }

        #pragma unroll
        for (int m = 0; m < 4; ++m) {
            const int node = base + wv * 4 + m;
            const float hv = acc[m];
            float pi = hv * ai;
            float pj = hv * aj;
            #pragma unroll
            for (int off = 32; off > 0; off >>= 1) {
                pi += __shfl_xor(pi, off, 64);
                pj += __shfl_xor(pj, off, 64);
            }
            if (node < n_nodes) {
                hb[(size_t)node * OUT_C + lane] = f2bf(hv);
                if (lane == 0) { s_i[node] = pi; s_j[node] = pj; }
            }
        }
    }
}

// ---------------------------------------------------------------------------
// Bucket histogram: LDS-privatized counts over NB buckets, flush via atomics.
// ---------------------------------------------------------------------------
__global__ __launch_bounds__(256) void zero_kernel(int* __restrict__ p, int n)
{
    const int i = blockIdx.x * 256 + threadIdx.x;
    if (i < n) p[i] = 0;
}

__global__ __launch_bounds__(256) void hist_bucket_kernel(
    const int* __restrict__ ei, int* __restrict__ counts, int n_edges, int nb)
{
    __shared__ int hist[MAXB];
    const int tid  = threadIdx.x;
    const int base = blockIdx.x * PCHUNK;
    const int lim  = min(PCHUNK, n_edges - base);

    for (int i = tid; i < nb; i += 256) hist[i] = 0;
    __syncthreads();
    for (int i = tid; i < lim; i += 256)
        atomicAdd(&hist[ei[n_edges + base + i] >> 7], 1);
    __syncthreads();
    for (int i = tid; i < nb; i += 256) {
        const int c = hist[i];
        if (c > 0) atomicAdd(&counts[i], c);
    }
}

// ---------------------------------------------------------------------------
// Exclusive scan over bucket counts (single block, nb <= 1024).
// ---------------------------------------------------------------------------
__global__ __launch_bounds__(256) void scan_buckets_kernel(
    const int* __restrict__ counts, int* __restrict__ offsets,
    int* __restrict__ cursor, int nb)
{
    __shared__ int sd[256];
    const int tid  = threadIdx.x;
    const int base = tid * 4;
    int v[4]; int ts = 0;
    #pragma unroll
    for (int j = 0; j < 4; ++j) {
        const int i = base + j;
        v[j] = (i < nb) ? counts[i] : 0;
        ts += v[j];
    }
    sd[tid] = ts;
    __syncthreads();
    for (int off = 1; off < 256; off <<= 1) {
        const int mine  = sd[tid];
        const int other = (tid >= off) ? sd[tid - off] : 0;
        __syncthreads();
        sd[tid] = mine + other;
        __syncthreads();
    }
    int run = sd[tid] - ts;
    #pragma unroll
    for (int j = 0; j < 4; ++j) {
        const int i = base + j;
        if (i < nb) { offsets[i] = run; cursor[i] = run; }
        run += v[j];
    }
}

// ---------------------------------------------------------------------------
// Partition: per-block two-phase (LDS hist -> bulk reserve -> write).
// Record = {r<<7 | (c&127), exp(lrelu(s_i[c]+s_j[r]))}, 8 B, bucket-contiguous.
// ---------------------------------------------------------------------------
__global__ __launch_bounds__(256) void partition_kernel(
    const int* __restrict__ ei, const float* __restrict__ s_i,
    const float* __restrict__ s_j, int* __restrict__ cursor,
    uint2* __restrict__ rec, int n_edges, int nb)
{
    __shared__ int hist[MAXB];
    __shared__ int lcur[MAXB];
    const int tid  = threadIdx.x;
    const int base = blockIdx.x * PCHUNK;
    const int lim  = min(PCHUNK, n_edges - base);

    for (int i = tid; i < nb; i += 256) hist[i] = 0;
    __syncthreads();
    for (int i = tid; i < lim; i += 256)
        atomicAdd(&hist[ei[n_edges + base + i] >> 7], 1);
    __syncthreads();
    for (int i = tid; i < nb; i += 256) {
        const int c = hist[i];
        lcur[i] = (c > 0) ? atomicAdd(&cursor[i], c) : 0;
    }
    __syncthreads();
    for (int i = tid; i < lim; i += 256) {
        const int r  = ei[base + i];
        const int c  = ei[n_edges + base + i];
        const float ex = lrelu_exp(s_i[c] + s_j[r]);
        const int pos = atomicAdd(&lcur[c >> 7], 1);
        rec[pos] = make_uint2(((uint32_t)r << 7) | (uint32_t)(c & (BKT - 1)),
                              __float_as_uint(ex));
    }
}

// ---------------------------------------------------------------------------
// Refine: block per bucket.  Stage the bucket's records in REGISTERS,
// LDS-histogram the 128 node slots, scan, then scatter records IN PLACE into
// exact per-node CSR order (writes stay inside this block's 32 KB window ->
// full-line merges in its own L2).  Emits nodeoff[] (global per-node starts).
// ---------------------------------------------------------------------------
__global__ __launch_bounds__(256) void refine_kernel(
    uint2* __restrict__ rec, const int* __restrict__ offsets,
    const int* __restrict__ counts, int* __restrict__ nodeoff,
    int n_nodes, int nb)
{
    __shared__ int hcnt[BKT];
    __shared__ int hscan[BKT];
    __shared__ int lcur[BKT];

    const int b     = blockIdx.x;
    const int tid   = threadIdx.x;
    const int start = offsets[b];
    int cnt = counts[b];
    if (cnt > CAP) cnt = CAP;   // +64 sigma guard; never triggers

    if (tid < BKT) hcnt[tid] = 0;
    __syncthreads();

    uint2 st[CAP / 256];
    #pragma unroll
    for (int k = 0; k < CAP / 256; ++k) {
        const int i = tid + (k << 8);
        if (i < cnt) {
            st[k] = rec[start + i];
            atomicAdd(&hcnt[st[k].x & (BKT - 1)], 1);
        }
    }
    __syncthreads();

    if (tid < BKT) hscan[tid] = hcnt[tid];
    __syncthreads();
    for (int off = 1; off < BKT; off <<= 1) {
        int v = 0;
        if (tid < BKT) { v = hscan[tid]; if (tid >= off) v += hscan[tid - off]; }
        __syncthreads();
        if (tid < BKT) hscan[tid] = v;
        __syncthreads();
    }
    if (tid < BKT) {
        const int excl = hscan[tid] - hcnt[tid];
        lcur[tid] = excl;
        const int g = b * BKT + tid;
        if (g < n_nodes) nodeoff[g] = start + excl;
    }
    if (b == nb - 1 && tid == 0) nodeoff[n_nodes] = start + cnt;
    __syncthreads();

    #pragma unroll
    for (int k = 0; k < CAP / 256; ++k) {
        const int i = tid + (k << 8);
        if (i < cnt) {
            const int n   = st[k].x & (BKT - 1);
            const int pos = atomicAdd(&lcur[n], 1);
            rec[start + pos] = st[k];
        }
    }
}

// ---------------------------------------------------------------------------
// Gather: one wave per destination node, register accumulation, no atomics.
// Records {r, ex} are wave-uniform scalar reads; h gathers are 128 B bf16.
// ---------------------------------------------------------------------------
__global__ __launch_bounds__(256) void gather_kernel(
    const uint2* __restrict__ rec, const ushort* __restrict__ hb,
    const float* __restrict__ s_i, const float* __restrict__ s_j,
    const int* __restrict__ nodeoff, float* __restrict__ out, int n_nodes)
{
    int wid = (int)((blockIdx.x * 256u + threadIdx.x) >> 6);
    wid = __builtin_amdgcn_readfirstlane(wid);
    if (wid >= n_nodes) return;
    const int lane = threadIdx.x & 63;

    const int o  = nodeoff[wid];
    const int oe = nodeoff[wid + 1];

    // self loop: row = col = node
    const float ex0 = lrelu_exp(s_i[wid] + s_j[wid]);
    float acc  = ex0 * bf2f(hb[(size_t)wid * OUT_C + lane]);
    float dsum = ex0;

    int e = o;
    for (; e + 4 <= oe; e += 4) {
        const uint2 r0 = rec[e + 0];
        const uint2 r1 = rec[e + 1];
        const uint2 r2 = rec[e + 2];
        const uint2 r3 = rec[e + 3];
        const float h0 = bf2f(hb[(size_t)(r0.x >> 7) * OUT_C + lane]);
        const float h1 = bf2f(hb[(size_t)(r1.x >> 7) * OUT_C + lane]);
        const float h2 = bf2f(hb[(size_t)(r2.x >> 7) * OUT_C + lane]);
        const float h3 = bf2f(hb[(size_t)(r3.x >> 7) * OUT_C + lane]);
        const float e0 = __uint_as_float(r0.y);
        const float e1 = __uint_as_float(r1.y);
        const float e2 = __uint_as_float(r2.y);
        const float e3 = __uint_as_float(r3.y);
        acc  += e0 * h0 + e1 * h1 + e2 * h2 + e3 * h3;
        dsum += e0 + e1 + e2 + e3;
    }
    for (; e < oe; ++e) {
        const uint2 rv = rec[e];
        const float ex = __uint_as_float(rv.y);
        acc  += ex * bf2f(hb[(size_t)(rv.x >> 7) * OUT_C + lane]);
        dsum += ex;
    }

    out[(size_t)wid * OUT_C + lane] = acc / dsum;
}

extern "C" void kernel_launch(void* const* d_in, const int* in_sizes, int n_in,
                              void* d_out, int out_size, void* d_ws, size_t ws_size,
                              hipStream_t stream)
{
    const float* x  = (const float*)d_in[0];
    const int*   ei = (const int*)d_in[1];
    const float* W  = (const float*)d_in[2];
    const float* a  = (const float*)d_in[3];

    const int N  = in_sizes[0] / IN_C;    // 100000
    const int E  = in_sizes[1] / 2;       // 3200000
    const int NB = (N + BKT - 1) / BKT;   // 782

    float* out = (float*)d_out;

    // workspace carve-up (~39.6 MB)
    char* ws = (char*)d_ws;
    ushort* hb      = (ushort*)ws;                ws += (size_t)N * OUT_C * 2;
    float*  s_i     = (float*)ws;                 ws += (size_t)N * 4;
    float*  s_j     = (float*)ws;                 ws += (size_t)N * 4;
    int*    counts  = (int*)ws;                   ws += (size_t)NB * 4;
    int*    offs    = (int*)ws;                   ws += (size_t)NB * 4;
    int*    cursor  = (int*)ws;                   ws += (size_t)NB * 4;
    int*    nodeoff = (int*)ws;                   ws += (size_t)(N + 1) * 4;
    ws = (char*)(((uintptr_t)ws + 15) & ~(uintptr_t)15);
    uint2*  rec     = (uint2*)ws;                 // E * 8 B

    // 1. projection + attention scores
    hipLaunchKernelGGL(fused_h_kernel, dim3(512), dim3(256), 0, stream,
                       x, W, a, hb, s_i, s_j, N);

    // 2. two-level sort of edges into per-node CSR
    hipLaunchKernelGGL(zero_kernel, dim3((NB + 255) / 256), dim3(256), 0, stream,
                       counts, NB);
    const int pblocks = (E + PCHUNK - 1) / PCHUNK;
    hipLaunchKernelGGL(hist_bucket_kernel, dim3(pblocks), dim3(256), 0, stream,
                       ei, counts, E, NB);
    hipLaunchKernelGGL(scan_buckets_kernel, dim3(1), dim3(256), 0, stream,
                       counts, offs, cursor, NB);
    hipLaunchKernelGGL(partition_kernel, dim3(pblocks), dim3(256), 0, stream,
                       ei, s_i, s_j, cursor, rec, E, NB);
    hipLaunchKernelGGL(refine_kernel, dim3(NB), dim3(256), 0, stream,
                       rec, offs, counts, nodeoff, N, NB);

    // 3. gather-aggregate (one wave per node, register accumulation)
    hipLaunchKernelGGL(gather_kernel, dim3((N + 3) / 4), dim3(256), 0, stream,
                       rec, hb, s_i, s_j, nodeoff, out, N);
}

// Round 5
// 416.192 us; speedup vs baseline: 4.4919x; 1.2732x over previous
//
#include <hip/hip_runtime.h>
#include <hip/hip_bf16.h>
#include <cstddef>
#include <cstdint>

#define IN_C 256
#define OUT_C 64
#define NEG_SLOPE 0.2f
#define BKT 128        // nodes per destination bucket (bucket = c >> 7)
#define PCHUNK 8192    // edges per block in hist/partition kernels
#define MAXB 1024      // LDS array size (>= number of buckets)
#define CAP 8192       // max records/bucket in refine (mean 4092, +64 sigma)

typedef __attribute__((ext_vector_type(4))) float f32x4;
typedef __attribute__((ext_vector_type(8))) short s16x8;

__device__ __forceinline__ float lrelu_exp(float t)
{
    t = (t >= 0.f) ? t : NEG_SLOPE * t;
    return __expf(t);
}

__device__ __forceinline__ float bf2f(ushort u)
{
    return __uint_as_float(((uint32_t)u) << 16);
}

__device__ __forceinline__ ushort f2bf(float f)
{
    uint32_t u = __float_as_uint(f);
    u += 0x7fffu + ((u >> 16) & 1u);   // round-to-nearest-even
    return (ushort)(u >> 16);
}

// pack two fp32 -> {bf16(f1)<<16 | bf16(f0)} with round-half-up
__device__ __forceinline__ uint32_t pack_bf2(float f0, float f1)
{
    const uint32_t u0 = __float_as_uint(f0) + 0x8000u;
    const uint32_t u1 = __float_as_uint(f1) + 0x8000u;
    return (u1 & 0xffff0000u) | (u0 >> 16);
}

// ---------------------------------------------------------------------------
// W -> bf16 B-fragment order: wfrag[((t*4+n)*64 + lane)*8 + j] = W[col][k],
// k = t*32 + (lane>>4)*8 + j, col = n*16 + (lane&15).  16384 ushorts = 32 KB.
// ---------------------------------------------------------------------------
__global__ __launch_bounds__(256) void wconv_kernel(
    const float* __restrict__ W, ushort* __restrict__ wfrag)
{
    const int idx = blockIdx.x * 256 + threadIdx.x;
    if (idx >= 32 * 64 * 8) return;
    const int j = idx & 7;
    const int l = (idx >> 3) & 63;
    const int n = (idx >> 9) & 3;
    const int t = idx >> 11;
    const int k   = t * 32 + ((l >> 4) << 3) + j;
    const int col = n * 16 + (l & 15);
    wfrag[idx] = f2bf(W[col * IN_C + k]);
}

// ---------------------------------------------------------------------------
// Kernel 1 (MFMA): h = x @ W^T (bf16 out), s_i = h@a_i, s_j = h@a_j (fp32).
// Block = 4 waves x 16 nodes = 64 nodes x 64 channels.  A-frags loaded
// directly from global x (coalesced, fragment layout), B-frags from LDS
// (conflict-free b128).  K = 8 steps of 32, 32 MFMA per wave.
// ---------------------------------------------------------------------------
__global__ __launch_bounds__(256) void fused_h_mfma(
    const float* __restrict__ x, const ushort* __restrict__ wfrag,
    const float* __restrict__ a, ushort* __restrict__ hb,
    float* __restrict__ s_i, float* __restrict__ s_j, int n_nodes)
{
    __shared__ ushort Bs[32 * 64 * 8];   // 32 KB

    const int tid = threadIdx.x;
    for (int i = tid; i < 2048; i += 256)
        ((float4*)Bs)[i] = ((const float4*)wfrag)[i];
    __syncthreads();

    const int lane = tid & 63;
    const int wv   = tid >> 6;
    const int m    = lane & 15;
    const int quad = lane >> 4;

    const int base = blockIdx.x * 64 + wv * 16;
    int row = base + m;
    if (row >= n_nodes) row = n_nodes - 1;   // clamped loads, masked stores

    f32x4 acc0 = {0.f, 0.f, 0.f, 0.f};
    f32x4 acc1 = {0.f, 0.f, 0.f, 0.f};
    f32x4 acc2 = {0.f, 0.f, 0.f, 0.f};
    f32x4 acc3 = {0.f, 0.f, 0.f, 0.f};

    const float* xrow = x + (size_t)row * IN_C + quad * 8;

    #pragma unroll
    for (int t = 0; t < 8; ++t) {
        const float4 xa = *(const float4*)(xrow + t * 32);
        const float4 xb = *(const float4*)(xrow + t * 32 + 4);
        union { s16x8 v; uint32_t u[4]; } af;
        af.u[0] = pack_bf2(xa.x, xa.y);
        af.u[1] = pack_bf2(xa.z, xa.w);
        af.u[2] = pack_bf2(xb.x, xb.y);
        af.u[3] = pack_bf2(xb.z, xb.w);

        const s16x8 b0 = *(const s16x8*)(Bs + ((t * 4 + 0) * 64 + lane) * 8);
        const s16x8 b1 = *(const s16x8*)(Bs + ((t * 4 + 1) * 64 + lane) * 8);
        const s16x8 b2 = *(const s16x8*)(Bs + ((t * 4 + 2) * 64 + lane) * 8);
        const s16x8 b3 = *(const s16x8*)(Bs + ((t * 4 + 3) * 64 + lane) * 8);

        acc0 = __builtin_amdgcn_mfma_f32_16x16x32_bf16(af.v, b0, acc0, 0, 0, 0);
        acc1 = __builtin_amdgcn_mfma_f32_16x16x32_bf16(af.v, b1, acc1, 0, 0, 0);
        acc2 = __builtin_amdgcn_mfma_f32_16x16x32_bf16(af.v, b2, acc2, 0, 0, 0);
        acc3 = __builtin_amdgcn_mfma_f32_16x16x32_bf16(af.v, b3, acc3, 0, 0, 0);
    }

    // epilogue: C/D layout col = lane&15, row = quad*4 + reg
    const int c0 = lane & 15;
    const float ai0 = a[c0],      ai1 = a[c0 + 16], ai2 = a[c0 + 32], ai3 = a[c0 + 48];
    const float aj0 = a[64 + c0], aj1 = a[80 + c0], aj2 = a[96 + c0], aj3 = a[112 + c0];

    #pragma unroll
    for (int r = 0; r < 4; ++r) {
        const int rowr = base + quad * 4 + r;
        float pi = acc0[r] * ai0 + acc1[r] * ai1 + acc2[r] * ai2 + acc3[r] * ai3;
        float pj = acc0[r] * aj0 + acc1[r] * aj1 + acc2[r] * aj2 + acc3[r] * aj3;
        pi += __shfl_xor(pi, 1, 64);  pj += __shfl_xor(pj, 1, 64);
        pi += __shfl_xor(pi, 2, 64);  pj += __shfl_xor(pj, 2, 64);
        pi += __shfl_xor(pi, 4, 64);  pj += __shfl_xor(pj, 4, 64);
        pi += __shfl_xor(pi, 8, 64);  pj += __shfl_xor(pj, 8, 64);
        if (rowr < n_nodes) {
            ushort* hr = hb + (size_t)rowr * OUT_C + c0;
            hr[0]  = f2bf(acc0[r]);
            hr[16] = f2bf(acc1[r]);
            hr[32] = f2bf(acc2[r]);
            hr[48] = f2bf(acc3[r]);
            if (c0 == 0) { s_i[rowr] = pi; s_j[rowr] = pj; }
        }
    }
}

// ---------------------------------------------------------------------------
// Bucket histogram: LDS-privatized counts over NB buckets, flush via atomics.
// ---------------------------------------------------------------------------
__global__ __launch_bounds__(256) void zero_kernel(int* __restrict__ p, int n)
{
    const int i = blockIdx.x * 256 + threadIdx.x;
    if (i < n) p[i] = 0;
}

__global__ __launch_bounds__(256) void hist_bucket_kernel(
    const int* __restrict__ ei, int* __restrict__ counts, int n_edges, int nb)
{
    __shared__ int hist[MAXB];
    const int tid  = threadIdx.x;
    const int base = blockIdx.x * PCHUNK;
    const int lim  = min(PCHUNK, n_edges - base);

    for (int i = tid; i < nb; i += 256) hist[i] = 0;
    __syncthreads();
    for (int i = tid; i < lim; i += 256)
        atomicAdd(&hist[ei[n_edges + base + i] >> 7], 1);
    __syncthreads();
    for (int i = tid; i < nb; i += 256) {
        const int c = hist[i];
        if (c > 0) atomicAdd(&counts[i], c);
    }
}

// ---------------------------------------------------------------------------
// Exclusive scan over bucket counts (single block, nb <= 1024).
// ---------------------------------------------------------------------------
__global__ __launch_bounds__(256) void scan_buckets_kernel(
    const int* __restrict__ counts, int* __restrict__ offsets,
    int* __restrict__ cursor, int nb)
{
    __shared__ int sd[256];
    const int tid  = threadIdx.x;
    const int base = tid * 4;
    int v[4]; int ts = 0;
    #pragma unroll
    for (int j = 0; j < 4; ++j) {
        const int i = base + j;
        v[j] = (i < nb) ? counts[i] : 0;
        ts += v[j];
    }
    sd[tid] = ts;
    __syncthreads();
    for (int off = 1; off < 256; off <<= 1) {
        const int mine  = sd[tid];
        const int other = (tid >= off) ? sd[tid - off] : 0;
        __syncthreads();
        sd[tid] = mine + other;
        __syncthreads();
    }
    int run = sd[tid] - ts;
    #pragma unroll
    for (int j = 0; j < 4; ++j) {
        const int i = base + j;
        if (i < nb) { offsets[i] = run; cursor[i] = run; }
        run += v[j];
    }
}

// ---------------------------------------------------------------------------
// Partition: per-block two-phase (LDS hist -> bulk reserve -> write).
// Record = {r<<7 | (c&127), exp(lrelu(s_i[c]+s_j[r]))}, 8 B, bucket-contiguous.
// ---------------------------------------------------------------------------
__global__ __launch_bounds__(256) void partition_kernel(
    const int* __restrict__ ei, const float* __restrict__ s_i,
    const float* __restrict__ s_j, int* __restrict__ cursor,
    uint2* __restrict__ rec, int n_edges, int nb)
{
    __shared__ int hist[MAXB];
    __shared__ int lcur[MAXB];
    const int tid  = threadIdx.x;
    const int base = blockIdx.x * PCHUNK;
    const int lim  = min(PCHUNK, n_edges - base);

    for (int i = tid; i < nb; i += 256) hist[i] = 0;
    __syncthreads();
    for (int i = tid; i < lim; i += 256)
        atomicAdd(&hist[ei[n_edges + base + i] >> 7], 1);
    __syncthreads();
    for (int i = tid; i < nb; i += 256) {
        const int c = hist[i];
        lcur[i] = (c > 0) ? atomicAdd(&cursor[i], c) : 0;
    }
    __syncthreads();
    for (int i = tid; i < lim; i += 256) {
        const int r  = ei[base + i];
        const int c  = ei[n_edges + base + i];
        const float ex = lrelu_exp(s_i[c] + s_j[r]);
        const int pos = atomicAdd(&lcur[c >> 7], 1);
        rec[pos] = make_uint2(((uint32_t)r << 7) | (uint32_t)(c & (BKT - 1)),
                              __float_as_uint(ex));
    }
}

// ---------------------------------------------------------------------------
// Refine: block per bucket.  Stage records in REGISTERS, LDS-histogram the
// 128 node slots, scan, scatter IN PLACE into per-node CSR order.
// ---------------------------------------------------------------------------
__global__ __launch_bounds__(256) void refine_kernel(
    uint2* __restrict__ rec, const int* __restrict__ offsets,
    const int* __restrict__ counts, int* __restrict__ nodeoff,
    int n_nodes, int nb)
{
    __shared__ int hcnt[BKT];
    __shared__ int hscan[BKT];
    __shared__ int lcur[BKT];

    const int b     = blockIdx.x;
    const int tid   = threadIdx.x;
    const int start = offsets[b];
    int cnt = counts[b];
    if (cnt > CAP) cnt = CAP;   // +64 sigma guard; never triggers

    if (tid < BKT) hcnt[tid] = 0;
    __syncthreads();

    uint2 st[CAP / 256];
    #pragma unroll
    for (int k = 0; k < CAP / 256; ++k) {
        const int i = tid + (k << 8);
        if (i < cnt) {
            st[k] = rec[start + i];
            atomicAdd(&hcnt[st[k].x & (BKT - 1)], 1);
        }
    }
    __syncthreads();

    if (tid < BKT) hscan[tid] = hcnt[tid];
    __syncthreads();
    for (int off = 1; off < BKT; off <<= 1) {
        int v = 0;
        if (tid < BKT) { v = hscan[tid]; if (tid >= off) v += hscan[tid - off]; }
        __syncthreads();
        if (tid < BKT) hscan[tid] = v;
        __syncthreads();
    }
    if (tid < BKT) {
        const int excl = hscan[tid] - hcnt[tid];
        lcur[tid] = excl;
        const int g = b * BKT + tid;
        if (g < n_nodes) nodeoff[g] = start + excl;
    }
    if (b == nb - 1 && tid == 0) nodeoff[n_nodes] = start + cnt;
    __syncthreads();

    #pragma unroll
    for (int k = 0; k < CAP / 256; ++k) {
        const int i = tid + (k << 8);
        if (i < cnt) {
            const int n   = st[k].x & (BKT - 1);
            const int pos = atomicAdd(&lcur[n], 1);
            rec[start + pos] = st[k];
        }
    }
}

// ---------------------------------------------------------------------------
// Gather: one wave per destination node, register accumulation, no atomics.
// Records {r, ex} are wave-uniform scalar reads; h gathers are 128 B bf16.
// Unroll 8 for memory-level parallelism.
// ---------------------------------------------------------------------------
__global__ __launch_bounds__(256) void gather_kernel(
    const uint2* __restrict__ rec, const ushort* __restrict__ hb,
    const float* __restrict__ s_i, const float* __restrict__ s_j,
    const int* __restrict__ nodeoff, float* __restrict__ out, int n_nodes)
{
    int wid = (int)((blockIdx.x * 256u + threadIdx.x) >> 6);
    wid = __builtin_amdgcn_readfirstlane(wid);
    if (wid >= n_nodes) return;
    const int lane = threadIdx.x & 63;

    const int o  = nodeoff[wid];
    const int oe = nodeoff[wid + 1];

    // self loop: row = col = node
    const float ex0 = lrelu_exp(s_i[wid] + s_j[wid]);
    float acc  = ex0 * bf2f(hb[(size_t)wid * OUT_C + lane]);
    float dsum = ex0;

    int e = o;
    for (; e + 8 <= oe; e += 8) {
        uint2 rv[8];
        #pragma unroll
        for (int q = 0; q < 8; ++q) rv[q] = rec[e + q];
        float hv[8];
        #pragma unroll
        for (int q = 0; q < 8; ++q)
            hv[q] = bf2f(hb[(size_t)(rv[q].x >> 7) * OUT_C + lane]);
        #pragma unroll
        for (int q = 0; q < 8; ++q) {
            const float ex = __uint_as_float(rv[q].y);
            acc  += ex * hv[q];
            dsum += ex;
        }
    }
    for (; e < oe; ++e) {
        const uint2 rv = rec[e];
        const float ex = __uint_as_float(rv.y);
        acc  += ex * bf2f(hb[(size_t)(rv.x >> 7) * OUT_C + lane]);
        dsum += ex;
    }

    out[(size_t)wid * OUT_C + lane] = acc / dsum;
}

extern "C" void kernel_launch(void* const* d_in, const int* in_sizes, int n_in,
                              void* d_out, int out_size, void* d_ws, size_t ws_size,
                              hipStream_t stream)
{
    const float* x  = (const float*)d_in[0];
    const int*   ei = (const int*)d_in[1];
    const float* W  = (const float*)d_in[2];
    const float* a  = (const float*)d_in[3];

    const int N  = in_sizes[0] / IN_C;    // 100000
    const int E  = in_sizes[1] / 2;       // 3200000
    const int NB = (N + BKT - 1) / BKT;   // 782

    float* out = (float*)d_out;

    // workspace carve-up (~39.7 MB)
    char* ws = (char*)d_ws;
    ushort* hb      = (ushort*)ws;                ws += (size_t)N * OUT_C * 2;
    float*  s_i     = (float*)ws;                 ws += (size_t)N * 4;
    float*  s_j     = (float*)ws;                 ws += (size_t)N * 4;
    int*    counts  = (int*)ws;                   ws += (size_t)NB * 4;
    int*    offs    = (int*)ws;                   ws += (size_t)NB * 4;
    int*    cursor  = (int*)ws;                   ws += (size_t)NB * 4;
    int*    nodeoff = (int*)ws;                   ws += (size_t)(N + 1) * 4;
    ws = (char*)(((uintptr_t)ws + 15) & ~(uintptr_t)15);
    ushort* wfrag   = (ushort*)ws;                ws += 32 * 64 * 8 * 2;   // 32 KB
    ws = (char*)(((uintptr_t)ws + 15) & ~(uintptr_t)15);
    uint2*  rec     = (uint2*)ws;                 // E * 8 B

    // 1. projection + attention scores (MFMA)
    hipLaunchKernelGGL(wconv_kernel, dim3(64), dim3(256), 0, stream, W, wfrag);
    hipLaunchKernelGGL(fused_h_mfma, dim3((N + 63) / 64), dim3(256), 0, stream,
                       x, wfrag, a, hb, s_i, s_j, N);

    // 2. two-level sort of edges into per-node CSR
    hipLaunchKernelGGL(zero_kernel, dim3((NB + 255) / 256), dim3(256), 0, stream,
                       counts, NB);
    const int pblocks = (E + PCHUNK - 1) / PCHUNK;
    hipLaunchKernelGGL(hist_bucket_kernel, dim3(pblocks), dim3(256), 0, stream,
                       ei, counts, E, NB);
    hipLaunchKernelGGL(scan_buckets_kernel, dim3(1), dim3(256), 0, stream,
                       counts, offs, cursor, NB);
    hipLaunchKernelGGL(partition_kernel, dim3(pblocks), dim3(256), 0, stream,
                       ei, s_i, s_j, cursor, rec, E, NB);
    hipLaunchKernelGGL(refine_kernel, dim3(NB), dim3(256), 0, stream,
                       rec, offs, counts, nodeoff, N, NB);

    // 3. gather-aggregate (one wave per node, register accumulation)
    hipLaunchKernelGGL(gather_kernel, dim3((N + 3) / 4), dim3(256), 0, stream,
                       rec, hb, s_i, s_j, nodeoff, out, N);
}

// Round 6
// 410.023 us; speedup vs baseline: 4.5595x; 1.0150x over previous
//
#include <hip/hip_runtime.h>
#include <hip/hip_bf16.h>
#include <cstddef>
#include <cstdint>

#define IN_C 256
#define OUT_C 64
#define NEG_SLOPE 0.2f
#define BKT2 512       // nodes per destination bucket (bucket = c >> 9)
#define PCHUNK 4096    // edges per block in hist/partition kernels
#define MAXB 256       // LDS array size (>= number of buckets = 196)
#define CAPL 18432     // LDS-staged records/bucket in refine (mean 16384, +16 sigma)
#define OVT 2          // per-thread register overflow slots (512 thr -> +1024, +24 sigma)

typedef __attribute__((ext_vector_type(4))) float f32x4;
typedef __attribute__((ext_vector_type(8))) short s16x8;

__device__ __forceinline__ float lrelu_exp(float t)
{
    t = (t >= 0.f) ? t : NEG_SLOPE * t;
    return __expf(t);
}

__device__ __forceinline__ float bf2f(ushort u)
{
    return __uint_as_float(((uint32_t)u) << 16);
}

__device__ __forceinline__ ushort f2bf(float f)
{
    uint32_t u = __float_as_uint(f);
    u += 0x7fffu + ((u >> 16) & 1u);   // round-to-nearest-even
    return (ushort)(u >> 16);
}

// pack two fp32 -> {bf16(f1)<<16 | bf16(f0)}
__device__ __forceinline__ uint32_t pack_bf2(float f0, float f1)
{
    const uint32_t u0 = __float_as_uint(f0) + 0x8000u;
    const uint32_t u1 = __float_as_uint(f1) + 0x8000u;
    return (u1 & 0xffff0000u) | (u0 >> 16);
}

// ---------------------------------------------------------------------------
// W -> bf16 B-fragment order: wfrag[((t*4+n)*64 + lane)*8 + j] = W[col][k],
// k = t*32 + (lane>>4)*8 + j, col = n*16 + (lane&15).  16384 ushorts = 32 KB.
// ---------------------------------------------------------------------------
__global__ __launch_bounds__(256) void wconv_kernel(
    const float* __restrict__ W, ushort* __restrict__ wfrag)
{
    const int idx = blockIdx.x * 256 + threadIdx.x;
    if (idx >= 32 * 64 * 8) return;
    const int j = idx & 7;
    const int l = (idx >> 3) & 63;
    const int n = (idx >> 9) & 3;
    const int t = idx >> 11;
    const int k   = t * 32 + ((l >> 4) << 3) + j;
    const int col = n * 16 + (l & 15);
    wfrag[idx] = f2bf(W[col * IN_C + k]);
}

// ---------------------------------------------------------------------------
// Kernel 1 (MFMA): h = x @ W^T (bf16 out), s_i = h@a_i, s_j = h@a_j (fp32).
// ---------------------------------------------------------------------------
__global__ __launch_bounds__(256) void fused_h_mfma(
    const float* __restrict__ x, const ushort* __restrict__ wfrag,
    const float* __restrict__ a, ushort* __restrict__ hb,
    float* __restrict__ s_i, float* __restrict__ s_j, int n_nodes)
{
    __shared__ ushort Bs[32 * 64 * 8];   // 32 KB

    const int tid = threadIdx.x;
    for (int i = tid; i < 2048; i += 256)
        ((float4*)Bs)[i] = ((const float4*)wfrag)[i];
    __syncthreads();

    const int lane = tid & 63;
    const int wv   = tid >> 6;
    const int m    = lane & 15;
    const int quad = lane >> 4;

    const int base = blockIdx.x * 64 + wv * 16;
    int row = base + m;
    if (row >= n_nodes) row = n_nodes - 1;   // clamped loads, masked stores

    f32x4 acc0 = {0.f, 0.f, 0.f, 0.f};
    f32x4 acc1 = {0.f, 0.f, 0.f, 0.f};
    f32x4 acc2 = {0.f, 0.f, 0.f, 0.f};
    f32x4 acc3 = {0.f, 0.f, 0.f, 0.f};

    const float* xrow = x + (size_t)row * IN_C + quad * 8;

    #pragma unroll
    for (int t = 0; t < 8; ++t) {
        const float4 xa = *(const float4*)(xrow + t * 32);
        const float4 xb = *(const float4*)(xrow + t * 32 + 4);
        union { s16x8 v; uint32_t u[4]; } af;
        af.u[0] = pack_bf2(xa.x, xa.y);
        af.u[1] = pack_bf2(xa.z, xa.w);
        af.u[2] = pack_bf2(xb.x, xb.y);
        af.u[3] = pack_bf2(xb.z, xb.w);

        const s16x8 b0 = *(const s16x8*)(Bs + ((t * 4 + 0) * 64 + lane) * 8);
        const s16x8 b1 = *(const s16x8*)(Bs + ((t * 4 + 1) * 64 + lane) * 8);
        const s16x8 b2 = *(const s16x8*)(Bs + ((t * 4 + 2) * 64 + lane) * 8);
        const s16x8 b3 = *(const s16x8*)(Bs + ((t * 4 + 3) * 64 + lane) * 8);

        acc0 = __builtin_amdgcn_mfma_f32_16x16x32_bf16(af.v, b0, acc0, 0, 0, 0);
        acc1 = __builtin_amdgcn_mfma_f32_16x16x32_bf16(af.v, b1, acc1, 0, 0, 0);
        acc2 = __builtin_amdgcn_mfma_f32_16x16x32_bf16(af.v, b2, acc2, 0, 0, 0);
        acc3 = __builtin_amdgcn_mfma_f32_16x16x32_bf16(af.v, b3, acc3, 0, 0, 0);
    }

    // epilogue: C/D layout col = lane&15, row = quad*4 + reg
    const int c0 = lane & 15;
    const float ai0 = a[c0],      ai1 = a[c0 + 16], ai2 = a[c0 + 32], ai3 = a[c0 + 48];
    const float aj0 = a[64 + c0], aj1 = a[80 + c0], aj2 = a[96 + c0], aj3 = a[112 + c0];

    #pragma unroll
    for (int r = 0; r < 4; ++r) {
        const int rowr = base + quad * 4 + r;
        float pi = acc0[r] * ai0 + acc1[r] * ai1 + acc2[r] * ai2 + acc3[r] * ai3;
        float pj = acc0[r] * aj0 + acc1[r] * aj1 + acc2[r] * aj2 + acc3[r] * aj3;
        pi += __shfl_xor(pi, 1, 64);  pj += __shfl_xor(pj, 1, 64);
        pi += __shfl_xor(pi, 2, 64);  pj += __shfl_xor(pj, 2, 64);
        pi += __shfl_xor(pi, 4, 64);  pj += __shfl_xor(pj, 4, 64);
        pi += __shfl_xor(pi, 8, 64);  pj += __shfl_xor(pj, 8, 64);
        if (rowr < n_nodes) {
            ushort* hr = hb + (size_t)rowr * OUT_C + c0;
            hr[0]  = f2bf(acc0[r]);
            hr[16] = f2bf(acc1[r]);
            hr[32] = f2bf(acc2[r]);
            hr[48] = f2bf(acc3[r]);
            if (c0 == 0) { s_i[rowr] = pi; s_j[rowr] = pj; }
        }
    }
}

// ---------------------------------------------------------------------------
// Bucket histogram over coarse 512-node buckets.
// ---------------------------------------------------------------------------
__global__ __launch_bounds__(256) void zero_kernel(int* __restrict__ p, int n)
{
    const int i = blockIdx.x * 256 + threadIdx.x;
    if (i < n) p[i] = 0;
}

__global__ __launch_bounds__(256) void hist_bucket_kernel(
    const int* __restrict__ ei, int* __restrict__ counts, int n_edges, int nb)
{
    __shared__ int hist[MAXB];
    const int tid  = threadIdx.x;
    const int base = blockIdx.x * PCHUNK;
    const int lim  = min(PCHUNK, n_edges - base);

    for (int i = tid; i < nb; i += 256) hist[i] = 0;
    __syncthreads();
    for (int i = tid; i < lim; i += 256)
        atomicAdd(&hist[(uint32_t)ei[n_edges + base + i] >> 9], 1);
    __syncthreads();
    for (int i = tid; i < nb; i += 256) {
        const int c = hist[i];
        if (c > 0) atomicAdd(&counts[i], c);
    }
}

// ---------------------------------------------------------------------------
// Exclusive scan over bucket counts (single block, nb <= 256).
// ---------------------------------------------------------------------------
__global__ __launch_bounds__(256) void scan_buckets_kernel(
    const int* __restrict__ counts, int* __restrict__ offsets,
    int* __restrict__ cursor, int nb)
{
    __shared__ int sd[256];
    const int tid = threadIdx.x;
    const int v = (tid < nb) ? counts[tid] : 0;
    sd[tid] = v;
    __syncthreads();
    for (int off = 1; off < 256; off <<= 1) {
        const int mine  = sd[tid];
        const int other = (tid >= off) ? sd[tid - off] : 0;
        __syncthreads();
        sd[tid] = mine + other;
        __syncthreads();
    }
    if (tid < nb) {
        const int excl = sd[tid] - v;
        offsets[tid] = excl;
        cursor[tid]  = excl;
    }
}

// ---------------------------------------------------------------------------
// Partition into coarse buckets: per-block two-phase (LDS hist -> bulk
// reserve -> write).  Record = {r<<9 | (c&511), exp(lrelu(s_i[c]+s_j[r]))}.
// Runs of ~21 records (168 B) per bucket per block -> low write amp.
// ---------------------------------------------------------------------------
__global__ __launch_bounds__(256) void partition_kernel(
    const int* __restrict__ ei, const float* __restrict__ s_i,
    const float* __restrict__ s_j, int* __restrict__ cursor,
    uint2* __restrict__ rec, int n_edges, int nb)
{
    __shared__ int hist[MAXB];
    __shared__ int lcur[MAXB];
    const int tid  = threadIdx.x;
    const int base = blockIdx.x * PCHUNK;
    const int lim  = min(PCHUNK, n_edges - base);

    for (int i = tid; i < nb; i += 256) hist[i] = 0;
    __syncthreads();
    for (int i = tid; i < lim; i += 256)
        atomicAdd(&hist[(uint32_t)ei[n_edges + base + i] >> 9], 1);
    __syncthreads();
    for (int i = tid; i < nb; i += 256) {
        const int c = hist[i];
        lcur[i] = (c > 0) ? atomicAdd(&cursor[i], c) : 0;
    }
    __syncthreads();
    for (int i = tid; i < lim; i += 256) {
        const int r  = ei[base + i];
        const int c  = ei[n_edges + base + i];
        const float ex = lrelu_exp(s_i[c] + s_j[r]);
        const int pos = atomicAdd(&lcur[(uint32_t)c >> 9], 1);
        rec[pos] = make_uint2(((uint32_t)r << 9) | (uint32_t)(c & (BKT2 - 1)),
                              __float_as_uint(ex));
    }
}

// ---------------------------------------------------------------------------
// Refine: one 512-thread block per 512-node bucket.  Stage ~16.4K records in
// LDS (144 KB), histogram + scan the 512 node slots, scatter into the
// bucket's contiguous global window (L2-merged full lines).  Register
// overflow path covers the +24-sigma tail.  Emits per-node nodeoff[].
// ---------------------------------------------------------------------------
__global__ __launch_bounds__(512) void refine_kernel(
    uint2* __restrict__ rec, const int* __restrict__ offsets,
    const int* __restrict__ counts, int* __restrict__ nodeoff,
    int n_nodes, int nb)
{
    __shared__ uint2 recs[CAPL];   // 144 KB
    __shared__ int hcnt[BKT2];     // 2 KB
    __shared__ int lcur[BKT2];     // 2 KB
    __shared__ int sscan[BKT2];    // 2 KB

    const int b     = blockIdx.x;
    const int tid   = threadIdx.x;
    const int start = offsets[b];
    const int cnt   = counts[b];
    const int cl    = min(cnt, CAPL);

    hcnt[tid] = 0;
    __syncthreads();

    // stage + histogram (LDS portion)
    for (int i = tid; i < cl; i += 512) {
        const uint2 rv = rec[start + i];
        recs[i] = rv;
        atomicAdd(&hcnt[rv.x & (BKT2 - 1)], 1);
    }
    // overflow -> registers (read BEFORE any scatter write; avoids WAR hazard)
    uint2 ov[OVT]; int nov = 0;
    for (int i = CAPL + tid; i < cnt; i += 512) {
        if (nov < OVT) {
            ov[nov] = rec[start + i];
            atomicAdd(&hcnt[ov[nov].x & (BKT2 - 1)], 1);
            ++nov;
        }
    }
    __syncthreads();

    // inclusive scan over 512 node counts
    const int myc = hcnt[tid];
    sscan[tid] = myc;
    __syncthreads();
    for (int off = 1; off < 512; off <<= 1) {
        const int mine  = sscan[tid];
        const int other = (tid >= off) ? sscan[tid - off] : 0;
        __syncthreads();
        sscan[tid] = mine + other;
        __syncthreads();
    }
    const int excl = sscan[tid] - myc;
    lcur[tid] = excl;
    const int g = b * BKT2 + tid;
    if (g < n_nodes) nodeoff[g] = start + excl;
    if (b == nb - 1 && tid == 0) nodeoff[n_nodes] = start + cnt;
    __syncthreads();

    // scatter LDS portion into per-node CSR order (within L2-resident window)
    for (int i = tid; i < cl; i += 512) {
        const uint2 rv = recs[i];
        const int pos = atomicAdd(&lcur[rv.x & (BKT2 - 1)], 1);
        rec[start + pos] = rv;
    }
    // scatter register overflow
    for (int k = 0; k < nov; ++k) {
        const int pos = atomicAdd(&lcur[ov[k].x & (BKT2 - 1)], 1);
        rec[start + pos] = ov[k];
    }
}

// ---------------------------------------------------------------------------
// Gather: one wave per destination node, register accumulation, no atomics.
// Unroll 16: sixteen independent 128 B bf16 gathers in flight per wave.
// ---------------------------------------------------------------------------
__global__ __launch_bounds__(256) void gather_kernel(
    const uint2* __restrict__ rec, const ushort* __restrict__ hb,
    const float* __restrict__ s_i, const float* __restrict__ s_j,
    const int* __restrict__ nodeoff, float* __restrict__ out, int n_nodes)
{
    int wid = (int)((blockIdx.x * 256u + threadIdx.x) >> 6);
    wid = __builtin_amdgcn_readfirstlane(wid);
    if (wid >= n_nodes) return;
    const int lane = threadIdx.x & 63;

    const int o  = nodeoff[wid];
    const int oe = nodeoff[wid + 1];

    // self loop: row = col = node
    const float ex0 = lrelu_exp(s_i[wid] + s_j[wid]);
    float acc  = ex0 * bf2f(hb[(size_t)wid * OUT_C + lane]);
    float dsum = ex0;

    int e = o;
    for (; e + 16 <= oe; e += 16) {
        uint2 rv[16];
        #pragma unroll
        for (int q = 0; q < 16; ++q) rv[q] = rec[e + q];
        float hv[16];
        #pragma unroll
        for (int q = 0; q < 16; ++q)
            hv[q] = bf2f(hb[(size_t)(rv[q].x >> 9) * OUT_C + lane]);
        #pragma unroll
        for (int q = 0; q < 16; ++q) {
            const float ex = __uint_as_float(rv[q].y);
            acc  += ex * hv[q];
            dsum += ex;
        }
    }
    for (; e + 4 <= oe; e += 4) {
        uint2 rv[4];
        #pragma unroll
        for (int q = 0; q < 4; ++q) rv[q] = rec[e + q];
        float hv[4];
        #pragma unroll
        for (int q = 0; q < 4; ++q)
            hv[q] = bf2f(hb[(size_t)(rv[q].x >> 9) * OUT_C + lane]);
        #pragma unroll
        for (int q = 0; q < 4; ++q) {
            const float ex = __uint_as_float(rv[q].y);
            acc  += ex * hv[q];
            dsum += ex;
        }
    }
    for (; e < oe; ++e) {
        const uint2 rv = rec[e];
        const float ex = __uint_as_float(rv.y);
        acc  += ex * bf2f(hb[(size_t)(rv.x >> 9) * OUT_C + lane]);
        dsum += ex;
    }

    out[(size_t)wid * OUT_C + lane] = acc / dsum;
}

extern "C" void kernel_launch(void* const* d_in, const int* in_sizes, int n_in,
                              void* d_out, int out_size, void* d_ws, size_t ws_size,
                              hipStream_t stream)
{
    const float* x  = (const float*)d_in[0];
    const int*   ei = (const int*)d_in[1];
    const float* W  = (const float*)d_in[2];
    const float* a  = (const float*)d_in[3];

    const int N  = in_sizes[0] / IN_C;     // 100000
    const int E  = in_sizes[1] / 2;        // 3200000
    const int NB = (N + BKT2 - 1) / BKT2;  // 196

    float* out = (float*)d_out;

    // workspace carve-up (~39.7 MB)
    char* ws = (char*)d_ws;
    ushort* hb      = (ushort*)ws;                ws += (size_t)N * OUT_C * 2;
    float*  s_i     = (float*)ws;                 ws += (size_t)N * 4;
    float*  s_j     = (float*)ws;                 ws += (size_t)N * 4;
    int*    counts  = (int*)ws;                   ws += (size_t)MAXB * 4;
    int*    offs    = (int*)ws;                   ws += (size_t)MAXB * 4;
    int*    cursor  = (int*)ws;                   ws += (size_t)MAXB * 4;
    int*    nodeoff = (int*)ws;                   ws += (size_t)(N + 1) * 4;
    ws = (char*)(((uintptr_t)ws + 15) & ~(uintptr_t)15);
    ushort* wfrag   = (ushort*)ws;                ws += 32 * 64 * 8 * 2;   // 32 KB
    ws = (char*)(((uintptr_t)ws + 15) & ~(uintptr_t)15);
    uint2*  rec     = (uint2*)ws;                 // E * 8 B

    // 1. projection + attention scores (MFMA)
    hipLaunchKernelGGL(wconv_kernel, dim3(64), dim3(256), 0, stream, W, wfrag);
    hipLaunchKernelGGL(fused_h_mfma, dim3((N + 63) / 64), dim3(256), 0, stream,
                       x, wfrag, a, hb, s_i, s_j, N);

    // 2. two-level sort of edges into per-node CSR (coarse 512-node buckets)
    hipLaunchKernelGGL(zero_kernel, dim3(1), dim3(256), 0, stream, counts, NB);
    const int pblocks = (E + PCHUNK - 1) / PCHUNK;
    hipLaunchKernelGGL(hist_bucket_kernel, dim3(pblocks), dim3(256), 0, stream,
                       ei, counts, E, NB);
    hipLaunchKernelGGL(scan_buckets_kernel, dim3(1), dim3(256), 0, stream,
                       counts, offs, cursor, NB);
    hipLaunchKernelGGL(partition_kernel, dim3(pblocks), dim3(256), 0, stream,
                       ei, s_i, s_j, cursor, rec, E, NB);
    hipLaunchKernelGGL(refine_kernel, dim3(NB), dim3(512), 0, stream,
                       rec, offs, counts, nodeoff, N, NB);

    // 3. gather-aggregate (one wave per node, register accumulation)
    hipLaunchKernelGGL(gather_kernel, dim3((N + 3) / 4), dim3(256), 0, stream,
                       rec, hb, s_i, s_j, nodeoff, out, N);
}

// Round 7
// 366.943 us; speedup vs baseline: 5.0947x; 1.1174x over previous
//
#include <hip/hip_runtime.h>
#include <hip/hip_bf16.h>
#include <cstddef>
#include <cstdint>

#define IN_C 256
#define OUT_C 64
#define NEG_SLOPE 0.2f
#define BKT2 512       // nodes per destination bucket (bucket = c >> 9)
#define PCHUNK 4096    // edges per block in hist/partition kernels
#define MAXB 256       // LDS array size (>= number of buckets = 196)
#define CAPL 18432     // LDS-staged records/bucket in refine (mean 16384, +16 sigma)
#define OVT 2          // per-thread register overflow slots (512 thr -> +1024, +24 sigma)

typedef __attribute__((ext_vector_type(4))) float f32x4;
typedef __attribute__((ext_vector_type(8))) short s16x8;

__device__ __forceinline__ float lrelu_exp(float t)
{
    t = (t >= 0.f) ? t : NEG_SLOPE * t;
    return __expf(t);
}

__device__ __forceinline__ float bf2f(ushort u)
{
    return __uint_as_float(((uint32_t)u) << 16);
}

__device__ __forceinline__ ushort f2bf(float f)
{
    uint32_t u = __float_as_uint(f);
    u += 0x7fffu + ((u >> 16) & 1u);   // round-to-nearest-even
    return (ushort)(u >> 16);
}

// pack two fp32 -> {bf16(f1)<<16 | bf16(f0)}
__device__ __forceinline__ uint32_t pack_bf2(float f0, float f1)
{
    const uint32_t u0 = __float_as_uint(f0) + 0x8000u;
    const uint32_t u1 = __float_as_uint(f1) + 0x8000u;
    return (u1 & 0xffff0000u) | (u0 >> 16);
}

// ---------------------------------------------------------------------------
// W -> bf16 B-fragment order: wfrag[((t*4+n)*64 + lane)*8 + j] = W[col][k],
// k = t*32 + (lane>>4)*8 + j, col = n*16 + (lane&15).  16384 ushorts = 32 KB.
// ---------------------------------------------------------------------------
__global__ __launch_bounds__(256) void wconv_kernel(
    const float* __restrict__ W, ushort* __restrict__ wfrag)
{
    const int idx = blockIdx.x * 256 + threadIdx.x;
    if (idx >= 32 * 64 * 8) return;
    const int j = idx & 7;
    const int l = (idx >> 3) & 63;
    const int n = (idx >> 9) & 3;
    const int t = idx >> 11;
    const int k   = t * 32 + ((l >> 4) << 3) + j;
    const int col = n * 16 + (l & 15);
    wfrag[idx] = f2bf(W[col * IN_C + k]);
}

// ---------------------------------------------------------------------------
// Kernel 1 (MFMA): h = x @ W^T (bf16 out), s_i = h@a_i, s_j = h@a_j (fp32).
// ---------------------------------------------------------------------------
__global__ __launch_bounds__(256) void fused_h_mfma(
    const float* __restrict__ x, const ushort* __restrict__ wfrag,
    const float* __restrict__ a, ushort* __restrict__ hb,
    float* __restrict__ s_i, float* __restrict__ s_j, int n_nodes)
{
    __shared__ ushort Bs[32 * 64 * 8];   // 32 KB

    const int tid = threadIdx.x;
    for (int i = tid; i < 2048; i += 256)
        ((float4*)Bs)[i] = ((const float4*)wfrag)[i];
    __syncthreads();

    const int lane = tid & 63;
    const int wv   = tid >> 6;
    const int m    = lane & 15;
    const int quad = lane >> 4;

    const int base = blockIdx.x * 64 + wv * 16;
    int row = base + m;
    if (row >= n_nodes) row = n_nodes - 1;   // clamped loads, masked stores

    f32x4 acc0 = {0.f, 0.f, 0.f, 0.f};
    f32x4 acc1 = {0.f, 0.f, 0.f, 0.f};
    f32x4 acc2 = {0.f, 0.f, 0.f, 0.f};
    f32x4 acc3 = {0.f, 0.f, 0.f, 0.f};

    const float* xrow = x + (size_t)row * IN_C + quad * 8;

    #pragma unroll
    for (int t = 0; t < 8; ++t) {
        const float4 xa = *(const float4*)(xrow + t * 32);
        const float4 xb = *(const float4*)(xrow + t * 32 + 4);
        union { s16x8 v; uint32_t u[4]; } af;
        af.u[0] = pack_bf2(xa.x, xa.y);
        af.u[1] = pack_bf2(xa.z, xa.w);
        af.u[2] = pack_bf2(xb.x, xb.y);
        af.u[3] = pack_bf2(xb.z, xb.w);

        const s16x8 b0 = *(const s16x8*)(Bs + ((t * 4 + 0) * 64 + lane) * 8);
        const s16x8 b1 = *(const s16x8*)(Bs + ((t * 4 + 1) * 64 + lane) * 8);
        const s16x8 b2 = *(const s16x8*)(Bs + ((t * 4 + 2) * 64 + lane) * 8);
        const s16x8 b3 = *(const s16x8*)(Bs + ((t * 4 + 3) * 64 + lane) * 8);

        acc0 = __builtin_amdgcn_mfma_f32_16x16x32_bf16(af.v, b0, acc0, 0, 0, 0);
        acc1 = __builtin_amdgcn_mfma_f32_16x16x32_bf16(af.v, b1, acc1, 0, 0, 0);
        acc2 = __builtin_amdgcn_mfma_f32_16x16x32_bf16(af.v, b2, acc2, 0, 0, 0);
        acc3 = __builtin_amdgcn_mfma_f32_16x16x32_bf16(af.v, b3, acc3, 0, 0, 0);
    }

    // epilogue: C/D layout col = lane&15, row = quad*4 + reg
    const int c0 = lane & 15;
    const float ai0 = a[c0],      ai1 = a[c0 + 16], ai2 = a[c0 + 32], ai3 = a[c0 + 48];
    const float aj0 = a[64 + c0], aj1 = a[80 + c0], aj2 = a[96 + c0], aj3 = a[112 + c0];

    #pragma unroll
    for (int r = 0; r < 4; ++r) {
        const int rowr = base + quad * 4 + r;
        float pi = acc0[r] * ai0 + acc1[r] * ai1 + acc2[r] * ai2 + acc3[r] * ai3;
        float pj = acc0[r] * aj0 + acc1[r] * aj1 + acc2[r] * aj2 + acc3[r] * aj3;
        pi += __shfl_xor(pi, 1, 64);  pj += __shfl_xor(pj, 1, 64);
        pi += __shfl_xor(pi, 2, 64);  pj += __shfl_xor(pj, 2, 64);
        pi += __shfl_xor(pi, 4, 64);  pj += __shfl_xor(pj, 4, 64);
        pi += __shfl_xor(pi, 8, 64);  pj += __shfl_xor(pj, 8, 64);
        if (rowr < n_nodes) {
            ushort* hr = hb + (size_t)rowr * OUT_C + c0;
            hr[0]  = f2bf(acc0[r]);
            hr[16] = f2bf(acc1[r]);
            hr[32] = f2bf(acc2[r]);
            hr[48] = f2bf(acc3[r]);
            if (c0 == 0) { s_i[rowr] = pi; s_j[rowr] = pj; }
        }
    }
}

// ---------------------------------------------------------------------------
// Bucket histogram over coarse 512-node buckets.
// ---------------------------------------------------------------------------
__global__ __launch_bounds__(256) void zero_kernel(int* __restrict__ p, int n)
{
    const int i = blockIdx.x * 256 + threadIdx.x;
    if (i < n) p[i] = 0;
}

__global__ __launch_bounds__(256) void hist_bucket_kernel(
    const int* __restrict__ ei, int* __restrict__ counts, int n_edges, int nb)
{
    __shared__ int hist[MAXB];
    const int tid  = threadIdx.x;
    const int base = blockIdx.x * PCHUNK;
    const int lim  = min(PCHUNK, n_edges - base);

    for (int i = tid; i < nb; i += 256) hist[i] = 0;
    __syncthreads();
    for (int i = tid; i < lim; i += 256)
        atomicAdd(&hist[(uint32_t)ei[n_edges + base + i] >> 9], 1);
    __syncthreads();
    for (int i = tid; i < nb; i += 256) {
        const int c = hist[i];
        if (c > 0) atomicAdd(&counts[i], c);
    }
}

// ---------------------------------------------------------------------------
// Exclusive scan over bucket counts (single block, nb <= 256).
// ---------------------------------------------------------------------------
__global__ __launch_bounds__(256) void scan_buckets_kernel(
    const int* __restrict__ counts, int* __restrict__ offsets,
    int* __restrict__ cursor, int nb)
{
    __shared__ int sd[256];
    const int tid = threadIdx.x;
    const int v = (tid < nb) ? counts[tid] : 0;
    sd[tid] = v;
    __syncthreads();
    for (int off = 1; off < 256; off <<= 1) {
        const int mine  = sd[tid];
        const int other = (tid >= off) ? sd[tid - off] : 0;
        __syncthreads();
        sd[tid] = mine + other;
        __syncthreads();
    }
    if (tid < nb) {
        const int excl = sd[tid] - v;
        offsets[tid] = excl;
        cursor[tid]  = excl;
    }
}

// ---------------------------------------------------------------------------
// Partition into coarse buckets with LDS reorder (radix-sort style):
// 1. load 16 edges/thread into registers, LDS histogram
// 2. block-local exclusive scan + one global atomicAdd per bucket (reserve)
// 3. scatter records into LDS staging in block-sorted order
// 4. linear flush LDS -> global: consecutive threads write consecutive
//    addresses within each run -> full-line coalesced bursts, minimal amp.
// ---------------------------------------------------------------------------
__global__ __launch_bounds__(256) void partition_kernel(
    const int* __restrict__ ei, const float* __restrict__ s_i,
    const float* __restrict__ s_j, int* __restrict__ cursor,
    uint2* __restrict__ rec, int n_edges, int nb)
{
    __shared__ int   hist[MAXB];
    __shared__ int   lbase[MAXB];
    __shared__ int   gbase[MAXB];
    __shared__ int   lcur[MAXB];
    __shared__ uint2 srt[PCHUNK];      // 32 KB staging
    __shared__ uint8_t bmap[PCHUNK];   // 4 KB bucket ids

    const int tid  = threadIdx.x;
    const int base = blockIdx.x * PCHUNK;
    const int lim  = min(PCHUNK, n_edges - base);

    for (int i = tid; i < MAXB; i += 256) hist[i] = 0;
    __syncthreads();

    int rA[PCHUNK / 256], cA[PCHUNK / 256];
    #pragma unroll
    for (int k = 0; k < PCHUNK / 256; ++k) {
        const int i = tid + (k << 8);
        if (i < lim) {
            rA[k] = ei[base + i];
            cA[k] = ei[n_edges + base + i];
            atomicAdd(&hist[(uint32_t)cA[k] >> 9], 1);
        }
    }
    __syncthreads();

    // block-local exclusive scan of hist (in lbase) + global reserve
    const int v = hist[tid];
    lbase[tid] = v;
    __syncthreads();
    for (int off = 1; off < 256; off <<= 1) {
        const int mine  = lbase[tid];
        const int other = (tid >= off) ? lbase[tid - off] : 0;
        __syncthreads();
        lbase[tid] = mine + other;
        __syncthreads();
    }
    const int excl = lbase[tid] - v;
    __syncthreads();
    lbase[tid] = excl;
    lcur[tid]  = excl;
    gbase[tid] = (tid < nb && v > 0) ? atomicAdd(&cursor[tid], v) : 0;
    __syncthreads();

    // scatter into LDS staging in sorted order
    #pragma unroll
    for (int k = 0; k < PCHUNK / 256; ++k) {
        const int i = tid + (k << 8);
        if (i < lim) {
            const int r = rA[k];
            const int c = cA[k];
            const int b = (uint32_t)c >> 9;
            const float ex = lrelu_exp(s_i[c] + s_j[r]);
            const int pos = atomicAdd(&lcur[b], 1);
            srt[pos]  = make_uint2(((uint32_t)r << 9) | (uint32_t)(c & (BKT2 - 1)),
                                   __float_as_uint(ex));
            bmap[pos] = (uint8_t)b;
        }
    }
    __syncthreads();

    // linear flush: piecewise-contiguous coalesced burst
    for (int i = tid; i < lim; i += 256) {
        const int b = bmap[i];
        rec[gbase[b] + (i - lbase[b])] = srt[i];
    }
}

// ---------------------------------------------------------------------------
// Refine: one 512-thread block per 512-node bucket.  Stage ~16.4K records in
// LDS (144 KB), histogram + scan the 512 node slots, scatter into the
// bucket's contiguous global window (L2-merged full lines).  Register
// overflow path covers the +24-sigma tail.  Emits per-node nodeoff[].
// ---------------------------------------------------------------------------
__global__ __launch_bounds__(512) void refine_kernel(
    uint2* __restrict__ rec, const int* __restrict__ offsets,
    const int* __restrict__ counts, int* __restrict__ nodeoff,
    int n_nodes, int nb)
{
    __shared__ uint2 recs[CAPL];   // 144 KB
    __shared__ int hcnt[BKT2];     // 2 KB
    __shared__ int lcur[BKT2];     // 2 KB
    __shared__ int sscan[BKT2];    // 2 KB

    const int b     = blockIdx.x;
    const int tid   = threadIdx.x;
    const int start = offsets[b];
    const int cnt   = counts[b];
    const int cl    = min(cnt, CAPL);

    hcnt[tid] = 0;
    __syncthreads();

    // stage + histogram (LDS portion)
    for (int i = tid; i < cl; i += 512) {
        const uint2 rv = rec[start + i];
        recs[i] = rv;
        atomicAdd(&hcnt[rv.x & (BKT2 - 1)], 1);
    }
    // overflow -> registers (read BEFORE any scatter write; avoids WAR hazard)
    uint2 ov[OVT]; int nov = 0;
    for (int i = CAPL + tid; i < cnt; i += 512) {
        if (nov < OVT) {
            ov[nov] = rec[start + i];
            atomicAdd(&hcnt[ov[nov].x & (BKT2 - 1)], 1);
            ++nov;
        }
    }
    __syncthreads();

    // inclusive scan over 512 node counts
    const int myc = hcnt[tid];
    sscan[tid] = myc;
    __syncthreads();
    for (int off = 1; off < 512; off <<= 1) {
        const int mine  = sscan[tid];
        const int other = (tid >= off) ? sscan[tid - off] : 0;
        __syncthreads();
        sscan[tid] = mine + other;
        __syncthreads();
    }
    const int excl = sscan[tid] - myc;
    lcur[tid] = excl;
    const int g = b * BKT2 + tid;
    if (g < n_nodes) nodeoff[g] = start + excl;
    if (b == nb - 1 && tid == 0) nodeoff[n_nodes] = start + cnt;
    __syncthreads();

    // scatter LDS portion into per-node CSR order (within L2-resident window)
    for (int i = tid; i < cl; i += 512) {
        const uint2 rv = recs[i];
        const int pos = atomicAdd(&lcur[rv.x & (BKT2 - 1)], 1);
        rec[start + pos] = rv;
    }
    // scatter register overflow
    for (int k = 0; k < nov; ++k) {
        const int pos = atomicAdd(&lcur[ov[k].x & (BKT2 - 1)], 1);
        rec[start + pos] = ov[k];
    }
}

// ---------------------------------------------------------------------------
// Gather: one wave per destination node, register accumulation, no atomics.
// Unroll 16: sixteen independent 128 B bf16 gathers in flight per wave.
// ---------------------------------------------------------------------------
__global__ __launch_bounds__(256) void gather_kernel(
    const uint2* __restrict__ rec, const ushort* __restrict__ hb,
    const float* __restrict__ s_i, const float* __restrict__ s_j,
    const int* __restrict__ nodeoff, float* __restrict__ out, int n_nodes)
{
    int wid = (int)((blockIdx.x * 256u + threadIdx.x) >> 6);
    wid = __builtin_amdgcn_readfirstlane(wid);
    if (wid >= n_nodes) return;
    const int lane = threadIdx.x & 63;

    const int o  = nodeoff[wid];
    const int oe = nodeoff[wid + 1];

    // self loop: row = col = node
    const float ex0 = lrelu_exp(s_i[wid] + s_j[wid]);
    float acc  = ex0 * bf2f(hb[(size_t)wid * OUT_C + lane]);
    float dsum = ex0;

    int e = o;
    for (; e + 16 <= oe; e += 16) {
        uint2 rv[16];
        #pragma unroll
        for (int q = 0; q < 16; ++q) rv[q] = rec[e + q];
        float hv[16];
        #pragma unroll
        for (int q = 0; q < 16; ++q)
            hv[q] = bf2f(hb[(size_t)(rv[q].x >> 9) * OUT_C + lane]);
        #pragma unroll
        for (int q = 0; q < 16; ++q) {
            const float ex = __uint_as_float(rv[q].y);
            acc  += ex * hv[q];
            dsum += ex;
        }
    }
    for (; e + 4 <= oe; e += 4) {
        uint2 rv[4];
        #pragma unroll
        for (int q = 0; q < 4; ++q) rv[q] = rec[e + q];
        float hv[4];
        #pragma unroll
        for (int q = 0; q < 4; ++q)
            hv[q] = bf2f(hb[(size_t)(rv[q].x >> 9) * OUT_C + lane]);
        #pragma unroll
        for (int q = 0; q < 4; ++q) {
            const float ex = __uint_as_float(rv[q].y);
            acc  += ex * hv[q];
            dsum += ex;
        }
    }
    for (; e < oe; ++e) {
        const uint2 rv = rec[e];
        const float ex = __uint_as_float(rv.y);
        acc  += ex * bf2f(hb[(size_t)(rv.x >> 9) * OUT_C + lane]);
        dsum += ex;
    }

    out[(size_t)wid * OUT_C + lane] = acc / dsum;
}

extern "C" void kernel_launch(void* const* d_in, const int* in_sizes, int n_in,
                              void* d_out, int out_size, void* d_ws, size_t ws_size,
                              hipStream_t stream)
{
    const float* x  = (const float*)d_in[0];
    const int*   ei = (const int*)d_in[1];
    const float* W  = (const float*)d_in[2];
    const float* a  = (const float*)d_in[3];

    const int N  = in_sizes[0] / IN_C;     // 100000
    const int E  = in_sizes[1] / 2;        // 3200000
    const int NB = (N + BKT2 - 1) / BKT2;  // 196

    float* out = (float*)d_out;

    // workspace carve-up (~39.7 MB)
    char* ws = (char*)d_ws;
    ushort* hb      = (ushort*)ws;                ws += (size_t)N * OUT_C * 2;
    float*  s_i     = (float*)ws;                 ws += (size_t)N * 4;
    float*  s_j     = (float*)ws;                 ws += (size_t)N * 4;
    int*    counts  = (int*)ws;                   ws += (size_t)MAXB * 4;
    int*    offs    = (int*)ws;                   ws += (size_t)MAXB * 4;
    int*    cursor  = (int*)ws;                   ws += (size_t)MAXB * 4;
    int*    nodeoff = (int*)ws;                   ws += (size_t)(N + 1) * 4;
    ws = (char*)(((uintptr_t)ws + 15) & ~(uintptr_t)15);
    ushort* wfrag   = (ushort*)ws;                ws += 32 * 64 * 8 * 2;   // 32 KB
    ws = (char*)(((uintptr_t)ws + 15) & ~(uintptr_t)15);
    uint2*  rec     = (uint2*)ws;                 // E * 8 B

    // 1. projection + attention scores (MFMA)
    hipLaunchKernelGGL(wconv_kernel, dim3(64), dim3(256), 0, stream, W, wfrag);
    hipLaunchKernelGGL(fused_h_mfma, dim3((N + 63) / 64), dim3(256), 0, stream,
                       x, wfrag, a, hb, s_i, s_j, N);

    // 2. two-level sort of edges into per-node CSR (coarse 512-node buckets)
    hipLaunchKernelGGL(zero_kernel, dim3(1), dim3(256), 0, stream, counts, NB);
    const int pblocks = (E + PCHUNK - 1) / PCHUNK;
    hipLaunchKernelGGL(hist_bucket_kernel, dim3(pblocks), dim3(256), 0, stream,
                       ei, counts, E, NB);
    hipLaunchKernelGGL(scan_buckets_kernel, dim3(1), dim3(256), 0, stream,
                       counts, offs, cursor, NB);
    hipLaunchKernelGGL(partition_kernel, dim3(pblocks), dim3(256), 0, stream,
                       ei, s_i, s_j, cursor, rec, E, NB);
    hipLaunchKernelGGL(refine_kernel, dim3(NB), dim3(512), 0, stream,
                       rec, offs, counts, nodeoff, N, NB);

    // 3. gather-aggregate (one wave per node, register accumulation)
    hipLaunchKernelGGL(gather_kernel, dim3((N + 3) / 4), dim3(256), 0, stream,
                       rec, hb, s_i, s_j, nodeoff, out, N);
}